// Round 6
// baseline (173.852 us; speedup 1.0000x reference)
//
#include <hip/hip_runtime.h>

// ClusteredAttention via bf16 MFMA, fragment-swizzled operands. B=2,L=2048,H=8,D=64.
//   kswz = bf16(log2e * sum_v key)  frag-linear   (pool role of prep kernel)
//   vswz = bf16(V) transposed+permuted frag-linear (vswz role of prep kernel)
//   S^T = K.Q (mfma 32x32x16; Q pre-scaled 1/8) ; P = exp2(S^T) ; O = P.V
//   out = O / rowsum(P)
//
// Round-6: r4's occupancy shape (1024 blk x 8 waves, qg=1, <=128 regs -> 16
// waves/CU) + r5's fused prep & exp2 fold + XCD-local bh swizzle (bh in LOW
// bid bits: each XCD's L2 holds ~1MB slice, not the whole 4.5MB) + explicit
// K AND V next-tile prefetch. r4 vs r5 showed occupancy and L2-traffic levers
// individually neutral at ~105us total; this round stacks every cheap win to
// test whether the plateau is kernel time or harness-fixed overhead.

#define BB 2
#define LL 2048
#define HH 8
#define DD 64

typedef __attribute__((ext_vector_type(8)))  short  short8;   // 8 bf16 = 4 VGPR
typedef __attribute__((ext_vector_type(16))) float  float16v; // 32x32 C/D frag

static __device__ inline unsigned short f2bf(float x) {       // RNE
    union { float f; unsigned u; } v; v.f = x;
    unsigned r = v.u + 0x7FFF + ((v.u >> 16) & 1);
    return (unsigned short)(r >> 16);
}
static __device__ inline unsigned pk_bf2(float x, float y) {
    return (unsigned)f2bf(x) | ((unsigned)f2bf(y) << 16);
}

// ------------------- fused prep: V-swizzle + K-pool-swizzle ------------------
// blocks [0,512): vswz role — chunk ((bh*64+T)*4 + t*2 + vh) is 1KB, lane
//   (half*32+ln) holds V[m=T*32+perm(t,half,jj)][s=vh*32+ln], jj=0..7.
// blocks [512,640): pool role — chunk ((b*64+T)*4+ks) is 1KB, lane (hf*32+ln)
//   holds log2e * sum_v key[b, T*32+ln, v, ks*16+hf*8 .. +8].
__global__ __launch_bounds__(256)
void prep_kernel(const float* __restrict__ key, const float* __restrict__ value,
                 unsigned short* __restrict__ kswz,
                 unsigned short* __restrict__ vswz) {
    __shared__ __align__(16) float Vl[64][68];
    int bid = blockIdx.x;
    int tid = threadIdx.x;

    if (bid < 512) {
        int mt = bid & 31, bh = bid >> 5;
        int h = bh & 7, b = bh >> 3;
        int m0 = mt * 64;
#pragma unroll
        for (int k = 0; k < 4; ++k) {
            int f = tid + k * 256;        // 64 rows x 16 float4
            int r = f >> 4;
            int cc = (f & 15) * 4;
            float4 t = *(const float4*)(value +
                (((size_t)(b * LL + m0 + r)) * HH + h) * DD + cc);
            *(float4*)&Vl[r][cc] = t;
        }
        __syncthreads();
#pragma unroll
        for (int k = 0; k < 2; ++k) {
            int c    = tid + k * 256;     // Tl(2) x t(2) x vh(2) x lane(64)
            int Tl   = c >> 8;
            int t    = (c >> 7) & 1;
            int vh   = (c >> 6) & 1;
            int lane = c & 63;
            int ln = lane & 31, half = lane >> 5;
            union { short8 v; unsigned short u[8]; } o;
#pragma unroll
            for (int jj = 0; jj < 8; ++jj) {
                int r2 = t * 8 + jj;
                int m  = (r2 & 3) + 8 * (r2 >> 2) + 4 * half;
                o.u[jj] = f2bf(Vl[Tl * 32 + m][vh * 32 + ln]);
            }
            *(short8*)(vswz +
                ((((size_t)bh * 64 + (mt * 2 + Tl)) * 4 + t * 2 + vh) * 512)
                + lane * 8) = o.v;
        }
    } else {
        const float LOG2E = 1.4426950408889634f;
        int pb    = bid - 512;            // [0,128)
        int chunk = pb * 4 + (tid >> 6);  // [0,512): ((b*64+T)*4+ks)
        int lane  = tid & 63;
        int b = chunk >> 8, T = (chunk >> 2) & 63, ks = chunk & 3;
        int ln = lane & 31, hf = lane >> 5;
        const float* base = key + (((size_t)(b * LL + T * 32 + ln)) * HH) * DD
                                + ks * 16 + hf * 8;
        float s[8];
#pragma unroll
        for (int j = 0; j < 8; ++j) s[j] = 0.f;
#pragma unroll
        for (int v = 0; v < HH; ++v) {
            float4 f0 = *(const float4*)(base + v * DD);
            float4 f1 = *(const float4*)(base + v * DD + 4);
            s[0] += f0.x; s[1] += f0.y; s[2] += f0.z; s[3] += f0.w;
            s[4] += f1.x; s[5] += f1.y; s[6] += f1.z; s[7] += f1.w;
        }
        union { short8 v; unsigned u[4]; } o;
#pragma unroll
        for (int i = 0; i < 4; ++i)
            o.u[i] = pk_bf2(s[2 * i] * LOG2E, s[2 * i + 1] * LOG2E);
        *(short8*)(kswz + (size_t)chunk * 512 + lane * 8) = o.v;
    }
}

// ------------------------------- main kernel --------------------------------
// 1024 blocks = bh(16, LOW bits: XCD-local) x qt(64 tiles of 32 q-rows).
// 8 waves x 64 lanes; wave wv owns keys [wv*256, wv*256+256) = tiles wv*8..+8.
__global__ __launch_bounds__(512, 4)
void attn_kernel(const float* __restrict__ query,
                 const unsigned short* __restrict__ kswz,
                 const unsigned short* __restrict__ vswz,
                 float* __restrict__ out) {
    int bid = blockIdx.x;
    int bh  = bid & 15;                // low bits -> same-bh blocks share XCD L2
    int qt  = bid >> 4;                // [0,64)
    int h = bh & 7, b = bh >> 3;

    int tid  = threadIdx.x;
    int lane = tid & 63;
    int wv   = tid >> 6;               // [0,8)
    int ln   = lane & 31;
    int half = lane >> 5;

    __shared__ float O4[4][32][DD];    // 32 KB two-stage combine
    __shared__ float lsumL[8][64];
    __shared__ float invL[32];

    // Q B-frags, pre-scaled by 1/8 (exact in bf16): B[k=s][n=qrow=ln]
    short8 qf[4];
    const float* qbase = query + (((size_t)(b * LL + qt * 32 + ln)) * HH + h) * DD;
#pragma unroll
    for (int ks = 0; ks < 4; ++ks) {
        const float4* qp = (const float4*)(qbase + ks * 16 + half * 8);
        float4 t0 = qp[0], t1 = qp[1];
        union { short8 v; unsigned u[4]; } uq;
        uq.u[0] = pk_bf2(t0.x * 0.125f, t0.y * 0.125f);
        uq.u[1] = pk_bf2(t0.z * 0.125f, t0.w * 0.125f);
        uq.u[2] = pk_bf2(t1.x * 0.125f, t1.y * 0.125f);
        uq.u[3] = pk_bf2(t1.z * 0.125f, t1.w * 0.125f);
        qf[ks] = uq.v;
    }

    const unsigned short* kp0 = kswz + (((size_t)b * 64 + wv * 8) * 4) * 512
                                     + (size_t)lane * 8;
    const unsigned short* vp0 = vswz + (((size_t)bh * 64 + wv * 8) * 4) * 512
                                     + (size_t)lane * 8;

    float16v o0, o1;
#pragma unroll
    for (int i = 0; i < 16; ++i) { o0[i] = 0.f; o1[i] = 0.f; }
    float lsa = 0.f, lsb = 0.f;

    short8 kf[4], vf[4];
#pragma unroll
    for (int ks = 0; ks < 4; ++ks) kf[ks] = *(const short8*)(kp0 + ks * 512);
#pragma unroll
    for (int u = 0; u < 4; ++u)    vf[u]  = *(const short8*)(vp0 + u * 512);

#pragma unroll
    for (int it = 0; it < 8; ++it) {
        // S^T = K.Q
        float16v sacc;
#pragma unroll
        for (int i = 0; i < 16; ++i) sacc[i] = 0.f;
#pragma unroll
        for (int ks = 0; ks < 4; ++ks)
            sacc = __builtin_amdgcn_mfma_f32_32x32x16_bf16(kf[ks], qf[ks], sacc, 0, 0, 0);

        // prefetch next tile's K and V while MFMA/exp run
        short8 kn[4], vn[4];
        if (it + 1 < 8) {
#pragma unroll
            for (int ks = 0; ks < 4; ++ks)
                kn[ks] = *(const short8*)(kp0 + (it + 1) * 2048 + ks * 512);
#pragma unroll
            for (int u = 0; u < 4; ++u)
                vn[u]  = *(const short8*)(vp0 + (it + 1) * 2048 + u * 512);
        }

        // exp2 (log2e folded into kswz, 1/8 into Q) + rowsum + perm-pack bf16
        union { short8 v[2]; unsigned u[8]; } pu;
#pragma unroll
        for (int i = 0; i < 8; ++i) {
            union { float f; unsigned u; } e0, e1;
            e0.f = exp2f(sacc[2 * i]);
            e1.f = exp2f(sacc[2 * i + 1]);
            lsa += e0.f; lsb += e1.f;
            pu.u[i] = __builtin_amdgcn_perm(e1.u + 0x8000u, e0.u + 0x8000u, 0x07060302u);
        }

        // O += P.V
        o0 = __builtin_amdgcn_mfma_f32_32x32x16_bf16(pu.v[0], vf[0], o0, 0, 0, 0);
        o1 = __builtin_amdgcn_mfma_f32_32x32x16_bf16(pu.v[0], vf[1], o1, 0, 0, 0);
        o0 = __builtin_amdgcn_mfma_f32_32x32x16_bf16(pu.v[1], vf[2], o0, 0, 0, 0);
        o1 = __builtin_amdgcn_mfma_f32_32x32x16_bf16(pu.v[1], vf[3], o1, 0, 0, 0);

        if (it + 1 < 8) {
#pragma unroll
            for (int ks = 0; ks < 4; ++ks) kf[ks] = kn[ks];
#pragma unroll
            for (int u = 0; u < 4; ++u)    vf[u]  = vn[u];
        }
    }

    // ---- epilogue: two-stage combine of 8 key-slice waves ----
    lsumL[wv][lane] = lsa + lsb;
    if (wv < 4) {
#pragma unroll
        for (int r = 0; r < 16; ++r) {
            int row = (r & 3) + 8 * (r >> 2) + 4 * half;
            O4[wv][row][ln]      = o0[r];
            O4[wv][row][32 + ln] = o1[r];
        }
    }
    __syncthreads();
    if (wv >= 4) {
#pragma unroll
        for (int r = 0; r < 16; ++r) {
            int row = (r & 3) + 8 * (r >> 2) + 4 * half;
            O4[wv - 4][row][ln]      += o0[r];
            O4[wv - 4][row][32 + ln] += o1[r];
        }
    }
    __syncthreads();

    if (tid < 32) {
        float s = 0.f;
#pragma unroll
        for (int w = 0; w < 8; ++w) s += lsumL[w][tid] + lsumL[w][tid + 32];
        invL[tid] = 1.0f / s;
    }
    __syncthreads();

    // 512 threads: each writes 4 floats of one output row
    int qrow = tid >> 4;               // [0,32)
    int c4   = (tid & 15) * 4;
    float inv = invL[qrow];
    float4 r;
    r.x = (O4[0][qrow][c4 + 0] + O4[1][qrow][c4 + 0] + O4[2][qrow][c4 + 0] + O4[3][qrow][c4 + 0]) * inv;
    r.y = (O4[0][qrow][c4 + 1] + O4[1][qrow][c4 + 1] + O4[2][qrow][c4 + 1] + O4[3][qrow][c4 + 1]) * inv;
    r.z = (O4[0][qrow][c4 + 2] + O4[1][qrow][c4 + 2] + O4[2][qrow][c4 + 2] + O4[3][qrow][c4 + 2]) * inv;
    r.w = (O4[0][qrow][c4 + 3] + O4[1][qrow][c4 + 3] + O4[2][qrow][c4 + 3] + O4[3][qrow][c4 + 3]) * inv;
    *(float4*)(out + (((size_t)(b * LL + qt * 32 + qrow)) * HH + h) * DD + c4) = r;
}

extern "C" void kernel_launch(void* const* d_in, const int* in_sizes, int n_in,
                              void* d_out, int out_size, void* d_ws, size_t ws_size,
                              hipStream_t stream) {
    const float* query = (const float*)d_in[0];
    const float* key   = (const float*)d_in[1];
    const float* value = (const float*)d_in[2];
    float* out = (float*)d_out;

    unsigned short* kswz = (unsigned short*)d_ws;                       // 512 KiB
    unsigned short* vswz = (unsigned short*)((char*)d_ws + 512 * 1024); // 4 MiB

    prep_kernel<<<640, 256, 0, stream>>>(key, value, kswz, vswz);
    attn_kernel<<<1024, 512, 0, stream>>>(query, kswz, vswz, out);
}

// Round 7
// 106.233 us; speedup vs baseline: 1.6365x; 1.6365x over previous
//
#include <hip/hip_runtime.h>

// ClusteredAttention via bf16 MFMA, fragment-swizzled operands. B=2,L=2048,H=8,D=64.
//   kswz = bf16(log2e * sum_v key)  frag-linear   (pool role of prep kernel)
//   vswz = bf16(V) transposed+permuted frag-linear (vswz role of prep kernel)
//   S^T = K.Q (mfma 32x32x16; Q pre-scaled 1/8) ; P = exp2(S^T) ; O = P.V
//   out = O / rowsum(P)
//
// MEASUREMENT MODEL (r4-r6): dur = ~54us fixed harness floor (256MiB d_ws
// poison fill ~44us + resets) + prep (~13us) + attn. r5 attn ~40us.
// ROUND-6 LESSON: __launch_bounds__(512,4) made the compiler cap VGPR at 64 ->
// ~190-reg working set spilled -> 376MB scratch traffic, attn 105us. Never
// 512-thread blocks + min-waves. This round: r5's qg=2 shape, loop reordered
// so depth-1 K/V prefetch reuses just-freed registers (S both groups -> K
// dead -> reload K; PV both groups -> V dead -> reload V), bounds (256,2).

#define BB 2
#define LL 2048
#define HH 8
#define DD 64

typedef __attribute__((ext_vector_type(8)))  short  short8;   // 8 bf16 = 4 VGPR
typedef __attribute__((ext_vector_type(16))) float  float16v; // 32x32 C/D frag

static __device__ inline unsigned short f2bf(float x) {       // RNE
    union { float f; unsigned u; } v; v.f = x;
    unsigned r = v.u + 0x7FFF + ((v.u >> 16) & 1);
    return (unsigned short)(r >> 16);
}
static __device__ inline unsigned pk_bf2(float x, float y) {
    return (unsigned)f2bf(x) | ((unsigned)f2bf(y) << 16);
}

// ------------------- fused prep: V-swizzle + K-pool-swizzle ------------------
// blocks [0,512): vswz role — chunk ((bh*64+T)*4 + t*2 + vh) is 1KB, lane
//   (half*32+ln) holds V[m=T*32+perm(t,half,jj)][s=vh*32+ln], jj=0..7.
// blocks [512,640): pool role — chunk ((b*64+T)*4+ks) is 1KB, lane (hf*32+ln)
//   holds log2e * sum_v key[b, T*32+ln, v, ks*16+hf*8 .. +8].
__global__ __launch_bounds__(256)
void prep_kernel(const float* __restrict__ key, const float* __restrict__ value,
                 unsigned short* __restrict__ kswz,
                 unsigned short* __restrict__ vswz) {
    __shared__ __align__(16) float Vl[64][68];
    int bid = blockIdx.x;
    int tid = threadIdx.x;

    if (bid < 512) {
        int mt = bid & 31, bh = bid >> 5;
        int h = bh & 7, b = bh >> 3;
        int m0 = mt * 64;
#pragma unroll
        for (int k = 0; k < 4; ++k) {
            int f = tid + k * 256;        // 64 rows x 16 float4
            int r = f >> 4;
            int cc = (f & 15) * 4;
            float4 t = *(const float4*)(value +
                (((size_t)(b * LL + m0 + r)) * HH + h) * DD + cc);
            *(float4*)&Vl[r][cc] = t;
        }
        __syncthreads();
#pragma unroll
        for (int k = 0; k < 2; ++k) {
            int c    = tid + k * 256;     // Tl(2) x t(2) x vh(2) x lane(64)
            int Tl   = c >> 8;
            int t    = (c >> 7) & 1;
            int vh   = (c >> 6) & 1;
            int lane = c & 63;
            int ln = lane & 31, half = lane >> 5;
            union { short8 v; unsigned short u[8]; } o;
#pragma unroll
            for (int jj = 0; jj < 8; ++jj) {
                int r2 = t * 8 + jj;
                int m  = (r2 & 3) + 8 * (r2 >> 2) + 4 * half;
                o.u[jj] = f2bf(Vl[Tl * 32 + m][vh * 32 + ln]);
            }
            *(short8*)(vswz +
                ((((size_t)bh * 64 + (mt * 2 + Tl)) * 4 + t * 2 + vh) * 512)
                + lane * 8) = o.v;
        }
    } else {
        const float LOG2E = 1.4426950408889634f;
        int pb    = bid - 512;            // [0,128)
        int chunk = pb * 4 + (tid >> 6);  // [0,512): ((b*64+T)*4+ks)
        int lane  = tid & 63;
        int b = chunk >> 8, T = (chunk >> 2) & 63, ks = chunk & 3;
        int ln = lane & 31, hf = lane >> 5;
        const float* base = key + (((size_t)(b * LL + T * 32 + ln)) * HH) * DD
                                + ks * 16 + hf * 8;
        float s[8];
#pragma unroll
        for (int j = 0; j < 8; ++j) s[j] = 0.f;
#pragma unroll
        for (int v = 0; v < HH; ++v) {
            float4 f0 = *(const float4*)(base + v * DD);
            float4 f1 = *(const float4*)(base + v * DD + 4);
            s[0] += f0.x; s[1] += f0.y; s[2] += f0.z; s[3] += f0.w;
            s[4] += f1.x; s[5] += f1.y; s[6] += f1.z; s[7] += f1.w;
        }
        union { short8 v; unsigned u[4]; } o;
#pragma unroll
        for (int i = 0; i < 4; ++i)
            o.u[i] = pk_bf2(s[2 * i] * LOG2E, s[2 * i + 1] * LOG2E);
        *(short8*)(kswz + (size_t)chunk * 512 + lane * 8) = o.v;
    }
}

// ------------------------------- main kernel --------------------------------
// 512 blocks = bh(16, LOW bits: XCD-local) x qt(32 tiles of 64 q-rows).
// 4 waves; wave wv owns keys [wv*512, wv*512+512) = tiles wv*16..+16.
// K/V frags reused across 2 q-groups (halves L2 traffic vs qg=1).
__global__ __launch_bounds__(256, 2)
void attn_kernel(const float* __restrict__ query,
                 const unsigned short* __restrict__ kswz,
                 const unsigned short* __restrict__ vswz,
                 float* __restrict__ out) {
    int bid = blockIdx.x;
    int bh  = bid & 15;                // low bits -> same-bh blocks share XCD L2
    int qt  = bid >> 4;                // [0,32), 64 q-rows each
    int h = bh & 7, b = bh >> 3;

    int tid  = threadIdx.x;
    int lane = tid & 63;
    int wv   = tid >> 6;
    int ln   = lane & 31;
    int half = lane >> 5;

    __shared__ float O2[2][64][68];    // pitch 68: breaks epilogue-read conflicts
    __shared__ float lsumL[4][128];
    __shared__ float invL[64];

    // Q B-frags for 2 q-groups, pre-scaled by 1/8 (exact in bf16)
    short8 qf[2][4];
#pragma unroll
    for (int g = 0; g < 2; ++g) {
        const float* qbase = query +
            (((size_t)(b * LL + qt * 64 + g * 32 + ln)) * HH + h) * DD;
#pragma unroll
        for (int ks = 0; ks < 4; ++ks) {
            const float4* qp = (const float4*)(qbase + ks * 16 + half * 8);
            float4 t0 = qp[0], t1 = qp[1];
            union { short8 v; unsigned u[4]; } uq;
            uq.u[0] = pk_bf2(t0.x * 0.125f, t0.y * 0.125f);
            uq.u[1] = pk_bf2(t0.z * 0.125f, t0.w * 0.125f);
            uq.u[2] = pk_bf2(t1.x * 0.125f, t1.y * 0.125f);
            uq.u[3] = pk_bf2(t1.z * 0.125f, t1.w * 0.125f);
            qf[g][ks] = uq.v;
        }
    }

    const unsigned short* kp0 = kswz + (((size_t)b * 64 + wv * 16) * 4) * 512
                                     + (size_t)lane * 8;
    const unsigned short* vp0 = vswz + (((size_t)bh * 64 + wv * 16) * 4) * 512
                                     + (size_t)lane * 8;

    float16v o00, o01, o10, o11;
#pragma unroll
    for (int i = 0; i < 16; ++i) { o00[i] = 0.f; o01[i] = 0.f; o10[i] = 0.f; o11[i] = 0.f; }
    float ls0a = 0.f, ls0b = 0.f, ls1a = 0.f, ls1b = 0.f;

    // preload tile 0
    short8 kf[4], vf[4];
#pragma unroll
    for (int ks = 0; ks < 4; ++ks) kf[ks] = *(const short8*)(kp0 + ks * 512);
#pragma unroll
    for (int u = 0; u < 4; ++u)    vf[u]  = *(const short8*)(vp0 + u * 512);

#pragma unroll
    for (int it = 0; it < 16; ++it) {
        // ---- S phase: both q-groups consume kf, then kf is dead ----
        float16v s0, s1;
#pragma unroll
        for (int i = 0; i < 16; ++i) { s0[i] = 0.f; s1[i] = 0.f; }
#pragma unroll
        for (int ks = 0; ks < 4; ++ks) {
            s0 = __builtin_amdgcn_mfma_f32_32x32x16_bf16(kf[ks], qf[0][ks], s0, 0, 0, 0);
            s1 = __builtin_amdgcn_mfma_f32_32x32x16_bf16(kf[ks], qf[1][ks], s1, 0, 0, 0);
        }
        // prefetch next K into the just-freed kf regs (hidden under exp+PV)
        if (it + 1 < 16) {
#pragma unroll
            for (int ks = 0; ks < 4; ++ks)
                kf[ks] = *(const short8*)(kp0 + (it + 1) * 2048 + ks * 512);
        }

        // ---- exp2 + rowsum + perm-pack for both groups ----
        union { short8 v[2]; unsigned u[8]; } pu0, pu1;
#pragma unroll
        for (int i = 0; i < 8; ++i) {
            union { float f; unsigned u; } e0, e1;
            e0.f = exp2f(s0[2 * i]);
            e1.f = exp2f(s0[2 * i + 1]);
            ls0a += e0.f; ls0b += e1.f;
            pu0.u[i] = __builtin_amdgcn_perm(e1.u + 0x8000u, e0.u + 0x8000u, 0x07060302u);
        }
#pragma unroll
        for (int i = 0; i < 8; ++i) {
            union { float f; unsigned u; } e0, e1;
            e0.f = exp2f(s1[2 * i]);
            e1.f = exp2f(s1[2 * i + 1]);
            ls1a += e0.f; ls1b += e1.f;
            pu1.u[i] = __builtin_amdgcn_perm(e1.u + 0x8000u, e0.u + 0x8000u, 0x07060302u);
        }

        // ---- PV phase: both q-groups consume vf, then vf is dead ----
        o00 = __builtin_amdgcn_mfma_f32_32x32x16_bf16(pu0.v[0], vf[0], o00, 0, 0, 0);
        o01 = __builtin_amdgcn_mfma_f32_32x32x16_bf16(pu0.v[0], vf[1], o01, 0, 0, 0);
        o10 = __builtin_amdgcn_mfma_f32_32x32x16_bf16(pu1.v[0], vf[0], o10, 0, 0, 0);
        o11 = __builtin_amdgcn_mfma_f32_32x32x16_bf16(pu1.v[0], vf[1], o11, 0, 0, 0);
        o00 = __builtin_amdgcn_mfma_f32_32x32x16_bf16(pu0.v[1], vf[2], o00, 0, 0, 0);
        o01 = __builtin_amdgcn_mfma_f32_32x32x16_bf16(pu0.v[1], vf[3], o01, 0, 0, 0);
        o10 = __builtin_amdgcn_mfma_f32_32x32x16_bf16(pu1.v[1], vf[2], o10, 0, 0, 0);
        o11 = __builtin_amdgcn_mfma_f32_32x32x16_bf16(pu1.v[1], vf[3], o11, 0, 0, 0);

        // prefetch next V into the just-freed vf regs (hidden under next S+exp)
        if (it + 1 < 16) {
#pragma unroll
            for (int u = 0; u < 4; ++u)
                vf[u] = *(const short8*)(vp0 + (it + 1) * 2048 + u * 512);
        }
    }

    // ---- epilogue: two-stage combine of 4 key-slice waves ----
    lsumL[wv][lane]      = ls0a + ls0b;
    lsumL[wv][64 + lane] = ls1a + ls1b;
    if (wv < 2) {
#pragma unroll
        for (int r = 0; r < 16; ++r) {
            int row = (r & 3) + 8 * (r >> 2) + 4 * half;
            O2[wv][row][ln]           = o00[r];
            O2[wv][row][32 + ln]      = o01[r];
            O2[wv][32 + row][ln]      = o10[r];
            O2[wv][32 + row][32 + ln] = o11[r];
        }
    }
    __syncthreads();
    if (wv >= 2) {
#pragma unroll
        for (int r = 0; r < 16; ++r) {
            int row = (r & 3) + 8 * (r >> 2) + 4 * half;
            O2[wv - 2][row][ln]           += o00[r];
            O2[wv - 2][row][32 + ln]      += o01[r];
            O2[wv - 2][32 + row][ln]      += o10[r];
            O2[wv - 2][32 + row][32 + ln] += o11[r];
        }
    }
    __syncthreads();

    if (tid < 64) {
        int g = tid >> 5, c = tid & 31;
        float s = 0.f;
#pragma unroll
        for (int w = 0; w < 4; ++w)
            s += lsumL[w][g * 64 + c] + lsumL[w][g * 64 + 32 + c];
        invL[tid] = 1.0f / s;
    }
    __syncthreads();

    int qrow = tid >> 2;               // [0,64)
    int c16  = (tid & 3) * 16;
    float inv = invL[qrow];
    float buf[16];
#pragma unroll
    for (int j = 0; j < 16; ++j)
        buf[j] = (O2[0][qrow][c16 + j] + O2[1][qrow][c16 + j]) * inv;
    float* ob = out + (((size_t)(b * LL + qt * 64 + qrow)) * HH + h) * DD + c16;
#pragma unroll
    for (int j = 0; j < 4; ++j)
        *(float4*)(ob + 4 * j) = make_float4(buf[4 * j], buf[4 * j + 1],
                                             buf[4 * j + 2], buf[4 * j + 3]);
}

extern "C" void kernel_launch(void* const* d_in, const int* in_sizes, int n_in,
                              void* d_out, int out_size, void* d_ws, size_t ws_size,
                              hipStream_t stream) {
    const float* query = (const float*)d_in[0];
    const float* key   = (const float*)d_in[1];
    const float* value = (const float*)d_in[2];
    float* out = (float*)d_out;

    unsigned short* kswz = (unsigned short*)d_ws;                       // 512 KiB
    unsigned short* vswz = (unsigned short*)((char*)d_ws + 512 * 1024); // 4 MiB

    prep_kernel<<<640, 256, 0, stream>>>(key, value, kswz, vswz);
    attn_kernel<<<512, 256, 0, stream>>>(query, kswz, vswz, out);
}

// Round 8
// 100.305 us; speedup vs baseline: 1.7332x; 1.0591x over previous
//
#include <hip/hip_runtime.h>

// ClusteredAttention via bf16 MFMA, fragment-swizzled operands. B=2,L=2048,H=8,D=64.
//   kswz = bf16(log2e * sum_v key)  frag-linear   (pool role of prep kernel)
//   vswz = bf16(V) transposed+permuted frag-linear (vswz role of prep kernel)
//   S^T = K.Q (mfma 32x32x16; Q pre-scaled 1/8) ; P = exp2(S^T) ; O = P.V
//   out = O / rowsum(P)
//
// MEASUREMENT MODEL (fit to r1-r7): dur = ~95us fixed per-replay harness cost
// (256MiB d_ws poison fill ~43us [measured in-profile] + 24MB input restore +
// d_out fill + replay overhead) + prep (~7us) + attn (~5-8us). Three different
// attn structures (r4/r5/r7) all landed 105-107us -> kernels are small; r6's
// +68us matches its 380MB spill traffic; r1's +390 matches its LDS-bound loop.
// ROUND-8: prep unchanged (isolate variable); attn only: native v_exp_f32
// (OCML exp2f has a ~5-instr denormal guard; args in [-30,30] so raw op exact)
// + 128 q-rows/block (halves L2 traffic to 135MB). If dur is flat again, the
// floor is confirmed and we're at the achievable ceiling.

#define BB 2
#define LL 2048
#define HH 8
#define DD 64

typedef __attribute__((ext_vector_type(8)))  short  short8;   // 8 bf16 = 4 VGPR
typedef __attribute__((ext_vector_type(16))) float  float16v; // 32x32 C/D frag

static __device__ inline unsigned short f2bf(float x) {       // RNE
    union { float f; unsigned u; } v; v.f = x;
    unsigned r = v.u + 0x7FFF + ((v.u >> 16) & 1);
    return (unsigned short)(r >> 16);
}
static __device__ inline unsigned pk_bf2(float x, float y) {
    return (unsigned)f2bf(x) | ((unsigned)f2bf(y) << 16);
}
static __device__ inline float fast_exp2(float x) {
#if __has_builtin(__builtin_amdgcn_exp2f)
    return __builtin_amdgcn_exp2f(x);   // raw v_exp_f32
#else
    return exp2f(x);
#endif
}

// ------------------- fused prep: V-swizzle + K-pool-swizzle ------------------
// (unchanged from r7 — known good)
__global__ __launch_bounds__(256)
void prep_kernel(const float* __restrict__ key, const float* __restrict__ value,
                 unsigned short* __restrict__ kswz,
                 unsigned short* __restrict__ vswz) {
    __shared__ __align__(16) float Vl[64][68];
    int bid = blockIdx.x;
    int tid = threadIdx.x;

    if (bid < 512) {
        int mt = bid & 31, bh = bid >> 5;
        int h = bh & 7, b = bh >> 3;
        int m0 = mt * 64;
#pragma unroll
        for (int k = 0; k < 4; ++k) {
            int f = tid + k * 256;        // 64 rows x 16 float4
            int r = f >> 4;
            int cc = (f & 15) * 4;
            float4 t = *(const float4*)(value +
                (((size_t)(b * LL + m0 + r)) * HH + h) * DD + cc);
            *(float4*)&Vl[r][cc] = t;
        }
        __syncthreads();
#pragma unroll
        for (int k = 0; k < 2; ++k) {
            int c    = tid + k * 256;     // Tl(2) x t(2) x vh(2) x lane(64)
            int Tl   = c >> 8;
            int t    = (c >> 7) & 1;
            int vh   = (c >> 6) & 1;
            int lane = c & 63;
            int ln = lane & 31, half = lane >> 5;
            union { short8 v; unsigned short u[8]; } o;
#pragma unroll
            for (int jj = 0; jj < 8; ++jj) {
                int r2 = t * 8 + jj;
                int m  = (r2 & 3) + 8 * (r2 >> 2) + 4 * half;
                o.u[jj] = f2bf(Vl[Tl * 32 + m][vh * 32 + ln]);
            }
            *(short8*)(vswz +
                ((((size_t)bh * 64 + (mt * 2 + Tl)) * 4 + t * 2 + vh) * 512)
                + lane * 8) = o.v;
        }
    } else {
        const float LOG2E = 1.4426950408889634f;
        int pb    = bid - 512;            // [0,128)
        int chunk = pb * 4 + (tid >> 6);  // [0,512): ((b*64+T)*4+ks)
        int lane  = tid & 63;
        int b = chunk >> 8, T = (chunk >> 2) & 63, ks = chunk & 3;
        int ln = lane & 31, hf = lane >> 5;
        const float* base = key + (((size_t)(b * LL + T * 32 + ln)) * HH) * DD
                                + ks * 16 + hf * 8;
        float s[8];
#pragma unroll
        for (int j = 0; j < 8; ++j) s[j] = 0.f;
#pragma unroll
        for (int v = 0; v < HH; ++v) {
            float4 f0 = *(const float4*)(base + v * DD);
            float4 f1 = *(const float4*)(base + v * DD + 4);
            s[0] += f0.x; s[1] += f0.y; s[2] += f0.z; s[3] += f0.w;
            s[4] += f1.x; s[5] += f1.y; s[6] += f1.z; s[7] += f1.w;
        }
        union { short8 v; unsigned u[4]; } o;
#pragma unroll
        for (int i = 0; i < 4; ++i)
            o.u[i] = pk_bf2(s[2 * i] * LOG2E, s[2 * i + 1] * LOG2E);
        *(short8*)(kswz + (size_t)chunk * 512 + lane * 8) = o.v;
    }
}

// ------------------------------- main kernel --------------------------------
// 256 blocks = bh(16, LOW bits: XCD-local L2) x qt(16 tiles of 128 q-rows).
// 8 waves of 512 thr; wave wv = (qh = wv&1, kh = wv>>1): q-half (64 rows as
// 2 groups of 32) x key-quarter (512 keys = 16 swizzle tiles). Inner loop is
// r7's proven qg=2 body (~190 VGPR); (512,2) -> 256 cap, no spill.
__global__ __launch_bounds__(512, 2)
void attn_kernel(const float* __restrict__ query,
                 const unsigned short* __restrict__ kswz,
                 const unsigned short* __restrict__ vswz,
                 float* __restrict__ out) {
    int bid = blockIdx.x;
    int bh  = bid & 15;                // bid%8 = XCD: bh i,i+8 share an XCD
    int qt  = bid >> 4;                // [0,16), 128 q-rows each
    int h = bh & 7, b = bh >> 3;

    int tid  = threadIdx.x;
    int lane = tid & 63;
    int wv   = tid >> 6;               // [0,8)
    int qh   = wv & 1;                 // q-half: rows qh*64 .. +64
    int kh   = wv >> 1;                // key-quarter: keys kh*512 .. +512
    int ln   = lane & 31;
    int half = lane >> 5;

    __shared__ float O2[2][64][68];    // 34.8 KB, reused across the 2 q-halves
    __shared__ float lsumL[8][128];
    __shared__ float invL[128];

    // Q B-frags for 2 q-groups of this q-half, pre-scaled by 1/8
    short8 qf[2][4];
#pragma unroll
    for (int g = 0; g < 2; ++g) {
        const float* qbase = query +
            (((size_t)(b * LL + qt * 128 + qh * 64 + g * 32 + ln)) * HH + h) * DD;
#pragma unroll
        for (int ks = 0; ks < 4; ++ks) {
            const float4* qp = (const float4*)(qbase + ks * 16 + half * 8);
            float4 t0 = qp[0], t1 = qp[1];
            union { short8 v; unsigned u[4]; } uq;
            uq.u[0] = pk_bf2(t0.x * 0.125f, t0.y * 0.125f);
            uq.u[1] = pk_bf2(t0.z * 0.125f, t0.w * 0.125f);
            uq.u[2] = pk_bf2(t1.x * 0.125f, t1.y * 0.125f);
            uq.u[3] = pk_bf2(t1.z * 0.125f, t1.w * 0.125f);
            qf[g][ks] = uq.v;
        }
    }

    const unsigned short* kp0 = kswz + (((size_t)b * 64 + kh * 16) * 4) * 512
                                     + (size_t)lane * 8;
    const unsigned short* vp0 = vswz + (((size_t)bh * 64 + kh * 16) * 4) * 512
                                     + (size_t)lane * 8;

    float16v o00, o01, o10, o11;
#pragma unroll
    for (int i = 0; i < 16; ++i) { o00[i] = 0.f; o01[i] = 0.f; o10[i] = 0.f; o11[i] = 0.f; }
    float ls0a = 0.f, ls0b = 0.f, ls1a = 0.f, ls1b = 0.f;

    short8 kf[4], vf[4];
#pragma unroll
    for (int ks = 0; ks < 4; ++ks) kf[ks] = *(const short8*)(kp0 + ks * 512);
#pragma unroll
    for (int u = 0; u < 4; ++u)    vf[u]  = *(const short8*)(vp0 + u * 512);

#pragma unroll
    for (int it = 0; it < 16; ++it) {
        // ---- S phase: both q-groups consume kf, then kf is dead ----
        float16v s0, s1;
#pragma unroll
        for (int i = 0; i < 16; ++i) { s0[i] = 0.f; s1[i] = 0.f; }
#pragma unroll
        for (int ks = 0; ks < 4; ++ks) {
            s0 = __builtin_amdgcn_mfma_f32_32x32x16_bf16(kf[ks], qf[0][ks], s0, 0, 0, 0);
            s1 = __builtin_amdgcn_mfma_f32_32x32x16_bf16(kf[ks], qf[1][ks], s1, 0, 0, 0);
        }
        if (it + 1 < 16) {             // prefetch next K into freed kf regs
#pragma unroll
            for (int ks = 0; ks < 4; ++ks)
                kf[ks] = *(const short8*)(kp0 + (it + 1) * 2048 + ks * 512);
        }

        // ---- exp2 (raw v_exp_f32) + rowsum + perm-pack for both groups ----
        union { short8 v[2]; unsigned u[8]; } pu0, pu1;
#pragma unroll
        for (int i = 0; i < 8; ++i) {
            union { float f; unsigned u; } e0, e1;
            e0.f = fast_exp2(s0[2 * i]);
            e1.f = fast_exp2(s0[2 * i + 1]);
            ls0a += e0.f; ls0b += e1.f;
            pu0.u[i] = __builtin_amdgcn_perm(e1.u + 0x8000u, e0.u + 0x8000u, 0x07060302u);
        }
#pragma unroll
        for (int i = 0; i < 8; ++i) {
            union { float f; unsigned u; } e0, e1;
            e0.f = fast_exp2(s1[2 * i]);
            e1.f = fast_exp2(s1[2 * i + 1]);
            ls1a += e0.f; ls1b += e1.f;
            pu1.u[i] = __builtin_amdgcn_perm(e1.u + 0x8000u, e0.u + 0x8000u, 0x07060302u);
        }

        // ---- PV phase: both q-groups consume vf, then vf is dead ----
        o00 = __builtin_amdgcn_mfma_f32_32x32x16_bf16(pu0.v[0], vf[0], o00, 0, 0, 0);
        o01 = __builtin_amdgcn_mfma_f32_32x32x16_bf16(pu0.v[0], vf[1], o01, 0, 0, 0);
        o10 = __builtin_amdgcn_mfma_f32_32x32x16_bf16(pu1.v[0], vf[0], o10, 0, 0, 0);
        o11 = __builtin_amdgcn_mfma_f32_32x32x16_bf16(pu1.v[0], vf[1], o11, 0, 0, 0);
        o00 = __builtin_amdgcn_mfma_f32_32x32x16_bf16(pu0.v[1], vf[2], o00, 0, 0, 0);
        o01 = __builtin_amdgcn_mfma_f32_32x32x16_bf16(pu0.v[1], vf[3], o01, 0, 0, 0);
        o10 = __builtin_amdgcn_mfma_f32_32x32x16_bf16(pu1.v[1], vf[2], o10, 0, 0, 0);
        o11 = __builtin_amdgcn_mfma_f32_32x32x16_bf16(pu1.v[1], vf[3], o11, 0, 0, 0);

        if (it + 1 < 16) {             // prefetch next V into freed vf regs
#pragma unroll
            for (int u = 0; u < 4; ++u)
                vf[u] = *(const short8*)(vp0 + (it + 1) * 2048 + u * 512);
        }
    }

    // ---- epilogue: sequential two-phase combine over the 2 q-halves ----
    lsumL[wv][lane]      = ls0a + ls0b;      // g0 per-lane partials
    lsumL[wv][64 + lane] = ls1a + ls1b;      // g1

    if (qh == 0 && kh < 2) {                 // phase A stage 1: write
#pragma unroll
        for (int r = 0; r < 16; ++r) {
            int row = (r & 3) + 8 * (r >> 2) + 4 * half;
            O2[kh][row][ln]           = o00[r];
            O2[kh][row][32 + ln]      = o01[r];
            O2[kh][32 + row][ln]      = o10[r];
            O2[kh][32 + row][32 + ln] = o11[r];
        }
    }
    __syncthreads();

    if (tid < 128) {                         // rowsum inverse for all 128 rows
        int qhh = tid >> 6, g = (tid >> 5) & 1, c = tid & 31;
        float s = 0.f;
#pragma unroll
        for (int k4 = 0; k4 < 4; ++k4) {
            int w = 2 * k4 + qhh;
            s += lsumL[w][g * 64 + c] + lsumL[w][g * 64 + 32 + c];
        }
        invL[tid] = 1.0f / s;
    }
    if (qh == 0 && kh >= 2) {                // phase A stage 2: accumulate
#pragma unroll
        for (int r = 0; r < 16; ++r) {
            int row = (r & 3) + 8 * (r >> 2) + 4 * half;
            O2[kh - 2][row][ln]           += o00[r];
            O2[kh - 2][row][32 + ln]      += o01[r];
            O2[kh - 2][32 + row][ln]      += o10[r];
            O2[kh - 2][32 + row][32 + ln] += o11[r];
        }
    }
    __syncthreads();

    {   // store rows [0,64)
        int R = tid >> 3, c8 = (tid & 7) * 8;
        float inv = invL[R];
        float* ob = out + (((size_t)(b * LL + qt * 128 + R)) * HH + h) * DD + c8;
        float4 r0, r1;
        r0.x = (O2[0][R][c8 + 0] + O2[1][R][c8 + 0]) * inv;
        r0.y = (O2[0][R][c8 + 1] + O2[1][R][c8 + 1]) * inv;
        r0.z = (O2[0][R][c8 + 2] + O2[1][R][c8 + 2]) * inv;
        r0.w = (O2[0][R][c8 + 3] + O2[1][R][c8 + 3]) * inv;
        r1.x = (O2[0][R][c8 + 4] + O2[1][R][c8 + 4]) * inv;
        r1.y = (O2[0][R][c8 + 5] + O2[1][R][c8 + 5]) * inv;
        r1.z = (O2[0][R][c8 + 6] + O2[1][R][c8 + 6]) * inv;
        r1.w = (O2[0][R][c8 + 7] + O2[1][R][c8 + 7]) * inv;
        *(float4*)ob = r0; *(float4*)(ob + 4) = r1;
    }
    __syncthreads();

    if (qh == 1 && kh < 2) {                 // phase B stage 1
#pragma unroll
        for (int r = 0; r < 16; ++r) {
            int row = (r & 3) + 8 * (r >> 2) + 4 * half;
            O2[kh][row][ln]           = o00[r];
            O2[kh][row][32 + ln]      = o01[r];
            O2[kh][32 + row][ln]      = o10[r];
            O2[kh][32 + row][32 + ln] = o11[r];
        }
    }
    __syncthreads();
    if (qh == 1 && kh >= 2) {                // phase B stage 2
#pragma unroll
        for (int r = 0; r < 16; ++r) {
            int row = (r & 3) + 8 * (r >> 2) + 4 * half;
            O2[kh - 2][row][ln]           += o00[r];
            O2[kh - 2][row][32 + ln]      += o01[r];
            O2[kh - 2][32 + row][ln]      += o10[r];
            O2[kh - 2][32 + row][32 + ln] += o11[r];
        }
    }
    __syncthreads();

    {   // store rows [64,128)
        int R = tid >> 3, c8 = (tid & 7) * 8;
        float inv = invL[64 + R];
        float* ob = out + (((size_t)(b * LL + qt * 128 + 64 + R)) * HH + h) * DD + c8;
        float4 r0, r1;
        r0.x = (O2[0][R][c8 + 0] + O2[1][R][c8 + 0]) * inv;
        r0.y = (O2[0][R][c8 + 1] + O2[1][R][c8 + 1]) * inv;
        r0.z = (O2[0][R][c8 + 2] + O2[1][R][c8 + 2]) * inv;
        r0.w = (O2[0][R][c8 + 3] + O2[1][R][c8 + 3]) * inv;
        r1.x = (O2[0][R][c8 + 4] + O2[1][R][c8 + 4]) * inv;
        r1.y = (O2[0][R][c8 + 5] + O2[1][R][c8 + 5]) * inv;
        r1.z = (O2[0][R][c8 + 6] + O2[1][R][c8 + 6]) * inv;
        r1.w = (O2[0][R][c8 + 7] + O2[1][R][c8 + 7]) * inv;
        *(float4*)ob = r0; *(float4*)(ob + 4) = r1;
    }
}

extern "C" void kernel_launch(void* const* d_in, const int* in_sizes, int n_in,
                              void* d_out, int out_size, void* d_ws, size_t ws_size,
                              hipStream_t stream) {
    const float* query = (const float*)d_in[0];
    const float* key   = (const float*)d_in[1];
    const float* value = (const float*)d_in[2];
    float* out = (float*)d_out;

    unsigned short* kswz = (unsigned short*)d_ws;                       // 512 KiB
    unsigned short* vswz = (unsigned short*)((char*)d_ws + 512 * 1024); // 4 MiB

    prep_kernel<<<640, 256, 0, stream>>>(key, value, kswz, vswz);
    attn_kernel<<<256, 512, 0, stream>>>(query, kswz, vswz, out);
}